// Round 1
// baseline (6151.414 us; speedup 1.0000x reference)
//
#include <hip/hip_runtime.h>
#include <math.h>

#define B_   4096
#define S_   64
#define H_   128
#define N_   (B_*S_)
#define ROWS 16
#define NTHR 512
#define GRID (B_/ROWS)

// ---- workspace float offsets ----
#define WS_WC    0        // [384][16]  combined obs->gi weights (padded f=16)
#define WS_BC    6144     // [384]      combined gi bias
#define WS_WAP   6528     // [128][16]  padded enc_air_w
#define WS_WQP   8576     // [128][128] wq * qln_w (folded)
#define WS_SQ    24960    // [128] row sums of wqp
#define WS_EQ    25088    // [128] wq@qln_b + bq
#define WS_KC    25216    // [128][4]  (wk*klnw)@enc_m_w
#define WS_EK1   25728    // [128] (wk*klnw)@enc_m_b
#define WS_SK    25856    // [128] rowsum(wk*klnw)
#define WS_EK2   25984    // [128] wk@kln_b + bk
#define WS_VC    26112    // [128][4]  wv@enc_m_w
#define WS_VB    26624    // [128] wv@enc_m_b + bv
#define WS_MV    26752    // [4] mean weights for keys_raw mean
#define WS_QQ    26756    // [16] 4x4 quadratic form for E[y^2]
#define WS_QLIN  26772    // [4]
#define WS_MBC   26776
#define WS_C0    26777

__device__ __forceinline__ float dot4(float4 a, float4 b){
    return fmaf(a.x,b.x, fmaf(a.y,b.y, fmaf(a.z,b.z, a.w*b.w)));
}
__device__ __forceinline__ void acc4(float& acc, float4 a, float4 b){
    acc = fmaf(a.x,b.x,acc); acc = fmaf(a.y,b.y,acc);
    acc = fmaf(a.z,b.z,acc); acc = fmaf(a.w,b.w,acc);
}

// ---------------- precompute folded weights ----------------
__global__ void precompute_kernel(
    const float* __restrict__ enc_air_w, const float* __restrict__ enc_air_b,
    const float* __restrict__ enc_m_w,  const float* __restrict__ enc_m_b,
    const float* __restrict__ gru_wih,  const float* __restrict__ gru_bih,
    const float* __restrict__ qln_w, const float* __restrict__ qln_b,
    const float* __restrict__ kln_w, const float* __restrict__ kln_b,
    const float* __restrict__ attn_in_w, const float* __restrict__ attn_in_b,
    float* __restrict__ ws)
{
    int i = blockIdx.x*blockDim.x + threadIdx.x;
    if (i < 6144) {                       // Wc[o][f] = sum_k wih[o][k]*Wa[k][f]
        int o = i>>4, f = i&15; float a = 0.f;
        if (f < 15) for (int k=0;k<128;k++) a = fmaf(gru_wih[o*128+k], enc_air_w[k*15+f], a);
        ws[WS_WC+i] = a;
    } else if (i < 6528) {                // bc
        int o = i-6144; float a = gru_bih[o];
        for (int k=0;k<128;k++) a = fmaf(gru_wih[o*128+k], enc_air_b[k], a);
        ws[WS_BC+o] = a;
    } else if (i < 8576) {                // Wap padded
        int idx = i-6528; int j = idx>>4, f = idx&15;
        ws[WS_WAP+idx] = (f<15) ? enc_air_w[j*15+f] : 0.f;
    } else if (i < 24960) {               // wqp
        int idx = i-8576; int o = idx>>7, j = idx&127;
        ws[WS_WQP+idx] = attn_in_w[o*128+j]*qln_w[j];
    } else if (i < 25088) {               // sq
        int o = i-24960; float a=0.f;
        for (int j=0;j<128;j++) a = fmaf(attn_in_w[o*128+j], qln_w[j], a);
        ws[WS_SQ+o]=a;
    } else if (i < 25216) {               // eq
        int o = i-25088; float a = attn_in_b[o];
        for (int j=0;j<128;j++) a = fmaf(attn_in_w[o*128+j], qln_b[j], a);
        ws[WS_EQ+o]=a;
    } else if (i < 25728) {               // Kc
        int idx = i-25216; int o = idx>>2, f = idx&3; float a=0.f;
        for (int j=0;j<128;j++) a = fmaf(attn_in_w[(128+o)*128+j]*kln_w[j], enc_m_w[j*4+f], a);
        ws[WS_KC+idx]=a;
    } else if (i < 25856) {               // ek1
        int o = i-25728; float a=0.f;
        for (int j=0;j<128;j++) a = fmaf(attn_in_w[(128+o)*128+j]*kln_w[j], enc_m_b[j], a);
        ws[WS_EK1+o]=a;
    } else if (i < 25984) {               // sk
        int o = i-25856; float a=0.f;
        for (int j=0;j<128;j++) a = fmaf(attn_in_w[(128+o)*128+j], kln_w[j], a);
        ws[WS_SK+o]=a;
    } else if (i < 26112) {               // ek2
        int o = i-25984; float a = attn_in_b[128+o];
        for (int j=0;j<128;j++) a = fmaf(attn_in_w[(128+o)*128+j], kln_b[j], a);
        ws[WS_EK2+o]=a;
    } else if (i < 26624) {               // Vc
        int idx = i-26112; int o = idx>>2, f = idx&3; float a=0.f;
        for (int j=0;j<128;j++) a = fmaf(attn_in_w[(256+o)*128+j], enc_m_w[j*4+f], a);
        ws[WS_VC+idx]=a;
    } else if (i < 26752) {               // vb
        int o = i-26624; float a = attn_in_b[256+o];
        for (int j=0;j<128;j++) a = fmaf(attn_in_w[(256+o)*128+j], enc_m_b[j], a);
        ws[WS_VB+o]=a;
    } else if (i < 26756) {               // Mv
        int f = i-26752; float a=0.f;
        for (int j=0;j<128;j++) a += enc_m_w[j*4+f];
        ws[WS_MV+f]=a*(1.f/128.f);
    } else if (i < 26772) {               // QQ
        int idx = i-26756; int a4 = idx>>2, b4 = idx&3; float a=0.f;
        for (int j=0;j<128;j++) a = fmaf(enc_m_w[j*4+a4], enc_m_w[j*4+b4], a);
        ws[WS_QQ+idx]=a*(1.f/128.f);
    } else if (i < 26776) {               // qlin
        int f = i-26772; float a=0.f;
        for (int j=0;j<128;j++) a = fmaf(enc_m_b[j], enc_m_w[j*4+f], a);
        ws[WS_QLIN+f]=a*(2.f/128.f);
    } else if (i == 26776) {
        float a=0.f; for (int j=0;j<128;j++) a += enc_m_b[j];
        ws[WS_MBC]=a*(1.f/128.f);
    } else if (i == 26777) {
        float a=0.f; for (int j=0;j<128;j++) a = fmaf(enc_m_b[j], enc_m_b[j], a);
        ws[WS_C0]=a*(1.f/128.f);
    }
}

// ---------------- fused GRU + attention + MLP ----------------
__global__ __launch_bounds__(NTHR) void fused_kernel(
    const float* __restrict__ obs, const float* __restrict__ h0,
    const float* __restrict__ whh, const float* __restrict__ bhh,
    const float* __restrict__ ba,
    const float* __restrict__ wo, const float* __restrict__ bo,
    const float* __restrict__ w0, const float* __restrict__ b0,
    const float* __restrict__ w1, const float* __restrict__ b1,
    const float* __restrict__ fcw, const float* __restrict__ fcb,
    const float* __restrict__ ws, float* __restrict__ out)
{
    __shared__ float h_s[ROWS][132];     // hidden state (pitch 132: 2-way banks, 16B aligned)
    __shared__ float X[ROWS][132];       // air_feat, later h2
    __shared__ float Ybuf[ROWS][132];    // combined (cb)
    __shared__ float Zbuf[ROWS][132];    // ctx, later h1
    __shared__ float obs_s[ROWS][16];
    __shared__ float red1[ROWS][33], red2[ROWS][33];
    __shared__ float sred[ROWS][33][2];
    __shared__ float attn_s[ROWS][4][2];
    __shared__ float mu_s[ROWS], rs_s[ROWS];
    __shared__ float kmu_s[ROWS][2], krs_s[ROWS][2];
    __shared__ int   kmask_s[ROWS][2];
    __shared__ int   bothm_s[ROWS];

    const int t  = threadIdx.x;
    const int r  = t & 15;
    const int g  = t >> 4;     // 0..31
    const int j0 = g * 4;
    const int row0 = blockIdx.x * ROWS;
    const int row  = row0 + r;

    // init hidden state from h0[0]
    #pragma unroll
    for (int jj=0;jj<4;jj++) h_s[r][j0+jj] = h0[row*H_ + j0 + jj];

    const float4* Wc4  = (const float4*)(ws + WS_WC);
    const float4* Wap4 = (const float4*)(ws + WS_WAP);
    const float4* whh4 = (const float4*)whh;
    const float4* wqp4 = (const float4*)(ws + WS_WQP);
    const float4* Kc4  = (const float4*)(ws + WS_KC);
    const float4* Vc4  = (const float4*)(ws + WS_VC);
    const float4* wo4  = (const float4*)wo;
    const float4* w04  = (const float4*)w0;
    const float4* w14  = (const float4*)w1;

    for (int s = 0; s < S_; ++s) {
        // ---- stage obs for this step ----
        if (t < 256) {
            int rr = t >> 4, c = t & 15;
            obs_s[rr][c] = (c < 15) ? obs[((row0+rr)*S_ + s)*15 + c] : 0.f;
        }
        __syncthreads();

        // ---- GRU gate dots: thread owns 4 gate columns j, computes r/z/n dots ----
        float accr[4], accz[4], gin[4], ghn[4];
        #pragma unroll
        for (int jj=0;jj<4;jj++){
            int oR = j0+jj, oZ = 128+j0+jj, oN = 256+j0+jj;
            accr[jj] = ws[WS_BC+oR] + bhh[oR];
            accz[jj] = ws[WS_BC+oZ] + bhh[oZ];
            gin[jj]  = ws[WS_BC+oN];
            ghn[jj]  = bhh[oN];
        }
        #pragma unroll
        for (int f4=0; f4<4; f4++){
            float4 ob = *(const float4*)&obs_s[r][f4*4];
            #pragma unroll
            for (int jj=0;jj<4;jj++){
                acc4(accr[jj], ob, Wc4[(      j0+jj)*4 + f4]);
                acc4(accz[jj], ob, Wc4[(128 + j0+jj)*4 + f4]);
                acc4(gin[jj],  ob, Wc4[(256 + j0+jj)*4 + f4]);
            }
        }
        #pragma unroll 2
        for (int k4=0;k4<32;k4++){
            float4 hv = *(const float4*)&h_s[r][k4*4];
            #pragma unroll
            for (int jj=0;jj<4;jj++){
                acc4(accr[jj], hv, whh4[(      j0+jj)*32 + k4]);
                acc4(accz[jj], hv, whh4[(128 + j0+jj)*32 + k4]);
                acc4(ghn[jj],  hv, whh4[(256 + j0+jj)*32 + k4]);
            }
        }
        float hold[4];
        #pragma unroll
        for (int jj=0;jj<4;jj++) hold[jj] = h_s[r][j0+jj];
        __syncthreads();   // all reads of h_s done

        // ---- gates + h update + air_feat ----
        #pragma unroll
        for (int jj=0;jj<4;jj++){
            float rg = 1.f/(1.f+expf(-accr[jj]));
            float zg = 1.f/(1.f+expf(-accz[jj]));
            float ng = tanhf(fmaf(rg, ghn[jj], gin[jj]));
            float hn = (1.f-zg)*ng + zg*hold[jj];
            h_s[r][j0+jj] = hn;
            float ae = ba[j0+jj];
            #pragma unroll
            for (int f4=0; f4<4; f4++){
                float4 ob = *(const float4*)&obs_s[r][f4*4];
                acc4(ae, ob, Wap4[(j0+jj)*4 + f4]);
            }
            X[r][j0+jj] = hn + ae;                         // air_feat
            if (s == S_-1) out[N_ + row*H_ + j0 + jj] = hn; // h_last
        }
        __syncthreads();

        // ---- S0: LN stats of air_feat + missile stats ----
        {
            float a=0.f, b2=0.f;
            #pragma unroll
            for (int jj=0;jj<4;jj++){ float v = X[r][j0+jj]; a += v; b2 = fmaf(v,v,b2); }
            red1[r][g]=a; red2[r][g]=b2;
        }
        __syncthreads();
        if (t < 16) {
            float a=0.f, b2=0.f;
            for (int k=0;k<32;k++){ a += red1[t][k]; b2 += red2[t][k]; }
            float mu = a*(1.f/128.f);
            float var = b2*(1.f/128.f) - mu*mu;
            mu_s[t]=mu; rs_s[t]=rsqrtf(var+1e-5f);
        } else if (t < 48) {
            int idx = t-16; int rr = idx&15; int mi = idx>>4;
            float m0=obs_s[rr][mi*4+0], m1=obs_s[rr][mi*4+1];
            float m2=obs_s[rr][mi*4+2], m3=obs_s[rr][mi*4+3];
            const float tol1 = 1e-8f + 1e-5f, tol0 = 1e-8f;
            kmask_s[rr][mi] = (fabsf(m0-1.f)<=tol1)&&(fabsf(m1)<=tol0)&&
                              (fabsf(m2-1.f)<=tol1)&&(fabsf(m3)<=tol0);
            float mv[4] = {m0,m1,m2,m3};
            float mu = ws[WS_MBC];
            for (int f=0;f<4;f++) mu = fmaf(ws[WS_MV+f], mv[f], mu);
            float e2 = ws[WS_C0];
            for (int a4=0;a4<4;a4++){
                e2 = fmaf(ws[WS_QLIN+a4], mv[a4], e2);
                for (int b4=0;b4<4;b4++) e2 = fmaf(ws[WS_QQ+a4*4+b4]*mv[a4], mv[b4], e2);
            }
            float var = e2 - mu*mu;
            kmu_s[rr][mi]=mu; krs_s[rr][mi]=rsqrtf(var+1e-5f);
        }
        __syncthreads();

        // ---- S1: q matvec (folded LN) + per-group score partials (k on the fly) ----
        {
            float acc[4] = {0.f,0.f,0.f,0.f};
            #pragma unroll 2
            for (int k4=0;k4<32;k4++){
                float4 xv = *(const float4*)&X[r][k4*4];
                #pragma unroll
                for (int jj=0;jj<4;jj++) acc4(acc[jj], xv, wqp4[(j0+jj)*32 + k4]);
            }
            float mu = mu_s[r], rs = rs_s[r];
            float4 m0v = *(const float4*)&obs_s[r][0];
            float4 m1v = *(const float4*)&obs_s[r][4];
            float km0 = kmu_s[r][0], km1 = kmu_s[r][1];
            float kr0 = krs_s[r][0], kr1 = krs_s[r][1];
            float p0=0.f, p1=0.f;
            #pragma unroll
            for (int jj=0;jj<4;jj++){
                int o = j0+jj;
                float q = fmaf(rs, acc[jj]-mu*ws[WS_SQ+o], ws[WS_EQ+o]);
                float4 kc = Kc4[o];
                float base = ws[WS_EK1+o], sko = ws[WS_SK+o], e2 = ws[WS_EK2+o];
                float k0 = fmaf(kr0, dot4(kc,m0v)+base-km0*sko, e2);
                float k1 = fmaf(kr1, dot4(kc,m1v)+base-km1*sko, e2);
                p0 = fmaf(q,k0,p0); p1 = fmaf(q,k1,p1);
            }
            sred[r][g][0]=p0; sred[r][g][1]=p1;
        }
        __syncthreads();

        // ---- S2: combine scores per head, softmax over 2 keys, mask handling ----
        if (t < 64) {
            int rr = t & 15, hd = t >> 4;
            float s0=0.f, s1=0.f;
            for (int k=0;k<8;k++){ s0 += sred[rr][hd*8+k][0]; s1 += sred[rr][hd*8+k][1]; }
            const float scale = 0.17677669529663687f;  // 1/sqrt(32)
            s0 *= scale; s1 *= scale;
            int m0 = kmask_s[rr][0], m1 = kmask_s[rr][1];
            float a0, a1;
            if (m0 && m1) { a0=0.f; a1=0.f; if (hd==0) bothm_s[rr]=1; }
            else {
                if (hd==0) bothm_s[rr]=0;
                if (m0)      { a0=0.f; a1=1.f; }
                else if (m1) { a0=1.f; a1=0.f; }
                else {
                    float mx = fmaxf(s0,s1);
                    float e0 = expf(s0-mx), e1 = expf(s1-mx);
                    float inv = 1.f/(e0+e1);
                    a0 = e0*inv; a1 = e1*inv;
                }
            }
            attn_s[rr][hd][0]=a0; attn_s[rr][hd][1]=a1;
        }
        __syncthreads();

        // ---- S3: ctx (v computed on the fly from folded Vc) ----
        {
            int hd = g >> 3;
            float a0 = attn_s[r][hd][0], a1 = attn_s[r][hd][1];
            float4 m0v = *(const float4*)&obs_s[r][0];
            float4 m1v = *(const float4*)&obs_s[r][4];
            #pragma unroll
            for (int jj=0;jj<4;jj++){
                int j = j0+jj;
                float4 vc = Vc4[j]; float vbj = ws[WS_VB+j];
                float v0 = dot4(vc,m0v)+vbj, v1 = dot4(vc,m1v)+vbj;
                Zbuf[r][j] = a0*v0 + a1*v1;
            }
        }
        __syncthreads();

        // ---- S4: attn_out matvec + nan guard + residual ----
        {
            float acc[4] = {0.f,0.f,0.f,0.f};
            #pragma unroll 2
            for (int k4=0;k4<32;k4++){
                float4 zv = *(const float4*)&Zbuf[r][k4*4];
                #pragma unroll
                for (int jj=0;jj<4;jj++) acc4(acc[jj], zv, wo4[(j0+jj)*32 + k4]);
            }
            int bm = bothm_s[r];
            #pragma unroll
            for (int jj=0;jj<4;jj++){
                int o = j0+jj;
                float ao = bm ? 0.f : (acc[jj] + bo[o]);
                Ybuf[r][o] = X[r][o] + ao;
            }
        }
        __syncthreads();

        // ---- S5: mlp0 + leaky relu -> Zbuf ----
        {
            float acc[4] = {0.f,0.f,0.f,0.f};
            #pragma unroll 2
            for (int k4=0;k4<32;k4++){
                float4 yv = *(const float4*)&Ybuf[r][k4*4];
                #pragma unroll
                for (int jj=0;jj<4;jj++) acc4(acc[jj], yv, w04[(j0+jj)*32 + k4]);
            }
            #pragma unroll
            for (int jj=0;jj<4;jj++){
                float v = acc[jj] + b0[j0+jj];
                Zbuf[r][j0+jj] = (v > 0.f) ? v : 0.01f*v;
            }
        }
        __syncthreads();

        // ---- S6: mlp1 + leaky relu -> X ----
        {
            float acc[4] = {0.f,0.f,0.f,0.f};
            #pragma unroll 2
            for (int k4=0;k4<32;k4++){
                float4 zv = *(const float4*)&Zbuf[r][k4*4];
                #pragma unroll
                for (int jj=0;jj<4;jj++) acc4(acc[jj], zv, w14[(j0+jj)*32 + k4]);
            }
            #pragma unroll
            for (int jj=0;jj<4;jj++){
                float v = acc[jj] + b1[j0+jj];
                X[r][j0+jj] = (v > 0.f) ? v : 0.01f*v;
            }
        }
        __syncthreads();

        // ---- S7: final dot with fco ----
        {
            float p = 0.f;
            #pragma unroll
            for (int jj=0;jj<4;jj++) p = fmaf(X[r][j0+jj], fcw[j0+jj], p);
            red1[r][g] = p;
        }
        __syncthreads();
        if (t < 16) {
            float a = 0.f;
            for (int k=0;k<32;k++) a += red1[t][k];
            out[(row0+t)*S_ + s] = a + fcb[0];
        }
        // top-of-loop barrier (after obs staging) protects reuse of shared buffers
    }
}

extern "C" void kernel_launch(void* const* d_in, const int* in_sizes, int n_in,
                              void* d_out, int out_size, void* d_ws, size_t ws_size,
                              hipStream_t stream) {
    const float* obs       = (const float*)d_in[0];
    const float* h0        = (const float*)d_in[1];
    const float* enc_air_w = (const float*)d_in[2];
    const float* enc_air_b = (const float*)d_in[3];
    const float* enc_m_w   = (const float*)d_in[4];
    const float* enc_m_b   = (const float*)d_in[5];
    const float* gru_wih   = (const float*)d_in[6];
    const float* gru_whh   = (const float*)d_in[7];
    const float* gru_bih   = (const float*)d_in[8];
    const float* gru_bhh   = (const float*)d_in[9];
    const float* qln_w     = (const float*)d_in[10];
    const float* qln_b     = (const float*)d_in[11];
    const float* kln_w     = (const float*)d_in[12];
    const float* kln_b     = (const float*)d_in[13];
    const float* attn_in_w = (const float*)d_in[14];
    const float* attn_in_b = (const float*)d_in[15];
    const float* attn_out_w= (const float*)d_in[16];
    const float* attn_out_b= (const float*)d_in[17];
    const float* mlp0_w    = (const float*)d_in[18];
    const float* mlp0_b    = (const float*)d_in[19];
    const float* mlp1_w    = (const float*)d_in[20];
    const float* mlp1_b    = (const float*)d_in[21];
    const float* fco_w     = (const float*)d_in[22];
    const float* fco_b     = (const float*)d_in[23];
    float* out = (float*)d_out;
    float* ws  = (float*)d_ws;

    precompute_kernel<<<dim3(105), dim3(256), 0, stream>>>(
        enc_air_w, enc_air_b, enc_m_w, enc_m_b, gru_wih, gru_bih,
        qln_w, qln_b, kln_w, kln_b, attn_in_w, attn_in_b, ws);

    fused_kernel<<<dim3(GRID), dim3(NTHR), 0, stream>>>(
        obs, h0, gru_whh, gru_bhh, enc_air_b,
        attn_out_w, attn_out_b, mlp0_w, mlp0_b, mlp1_w, mlp1_b,
        fco_w, fco_b, ws, out);
}